// Round 1
// baseline (98.291 us; speedup 1.0000x reference)
//
#include <hip/hip_runtime.h>
#include <math.h>

#define KSEL 32
#define DDIM 256
#define SDIM 256
#define SM1 255
#define EPSN 1e-12f

__global__ __launch_bounds__(256) void matching_reducer_kernel(
    const float* __restrict__ nse,   // (B,H,S,D) news_selection_embedding
    const float* __restrict__ ne,    // (B,H,S,D) news_embedding
    const float* __restrict__ ur,    // (B,1,D)   user_repr
    const float* __restrict__ am,    // (B,H,S)   his_attn_mask
    const int*   __restrict__ rm,    // (B,H,S)   his_refined_mask
    const float* __restrict__ seg,   // (H,1,D)   segment_embedding
    float* __restrict__ out_terms,   // (B,H*K,D)
    float* __restrict__ out_mask,    // (B,H*K)
    float* __restrict__ out_kid,     // (B,H*K)   indices as float
    int H)
{
    const int bh   = blockIdx.x;
    const int b    = bh / H;
    const int h    = bh % H;
    const int tid  = threadIdx.x;
    const int lane = tid & 63;
    const int wave = tid >> 6;

    __shared__ float  s_scores[SM1 + 1];
    __shared__ float  s_sk[KSEL];
    __shared__ int    s_kid[KSEL];
    __shared__ float  s_w[KSEL];
    __shared__ float4 s_seg[64];

    // stage segment embedding row for this h
    if (tid < 64) {
        s_seg[tid] = reinterpret_cast<const float4*>(seg + (size_t)h * DDIM)[tid];
    }

    // per-lane fragment of the user vector (same for all 4 waves)
    float4 q4 = reinterpret_cast<const float4*>(ur + (size_t)b * DDIM)[lane];
    float qq = q4.x * q4.x + q4.y * q4.y + q4.z * q4.z + q4.w * q4.w;
    #pragma unroll
    for (int o = 32; o > 0; o >>= 1) qq += __shfl_xor(qq, o, 64);
    const float inv_q = 1.0f / fmaxf(sqrtf(qq), EPSN);

    // ---- score pass: wave w owns rows [w*64, min(255, w*64+64)) ----
    const float* selb = nse + ((size_t)bh * SDIM + 1) * DDIM;
    const int*   rmb  = rm + (size_t)bh * SDIM + 1;
    const int rbeg = wave * 64;
    const int rend = min(SM1, rbeg + 64);
    for (int r0 = rbeg; r0 < rend; r0 += 4) {
        float dot[4], ss[4];
        #pragma unroll
        for (int j = 0; j < 4; ++j) {
            const int r = r0 + j;
            if (r < rend) {
                float4 x = reinterpret_cast<const float4*>(selb + (size_t)r * DDIM)[lane];
                dot[j] = x.x * q4.x + x.y * q4.y + x.z * q4.z + x.w * q4.w;
                ss[j]  = x.x * x.x + x.y * x.y + x.z * x.z + x.w * x.w;
            } else {
                dot[j] = 0.0f; ss[j] = 0.0f;
            }
        }
        #pragma unroll
        for (int j = 0; j < 4; ++j) {
            float dv = dot[j], sv = ss[j];
            #pragma unroll
            for (int o = 32; o > 0; o >>= 1) {
                dv += __shfl_xor(dv, o, 64);
                sv += __shfl_xor(sv, o, 64);
            }
            const int r = r0 + j;
            if (r < rend && lane == 0) {
                float score = dv * inv_q / fmaxf(sqrtf(sv), EPSN);
                // valid = refined_mask + keep_k != 0  (keep_k = 1 for first K slots)
                bool valid = ((float)rmb[r] + (r < KSEL ? 1.0f : 0.0f)) != 0.0f;
                s_scores[r] = valid ? score : -INFINITY;
            }
        }
    }
    __syncthreads();

    // ---- top-K (wave 0 only): iterative argmax, tie -> smallest index ----
    if (wave == 0) {
        float v[4];
        #pragma unroll
        for (int j = 0; j < 4; ++j) {
            const int idx = lane + 64 * j;
            v[j] = (idx < SM1) ? s_scores[idx] : -INFINITY;
        }
        for (int k = 0; k < KSEL; ++k) {
            float bv = v[0];
            int   bi = lane;
            #pragma unroll
            for (int j = 1; j < 4; ++j) {
                const int idx = lane + 64 * j;
                if (v[j] > bv || (v[j] == bv && idx < bi)) { bv = v[j]; bi = idx; }
            }
            #pragma unroll
            for (int o = 32; o > 0; o >>= 1) {
                float ov = __shfl_xor(bv, o, 64);
                int   oi = __shfl_xor(bi, o, 64);
                if (ov > bv || (ov == bv && oi < bi)) { bv = ov; bi = oi; }
            }
            if (lane == 0) { s_sk[k] = bv; s_kid[k] = bi; }
            if ((bi & 63) == lane) v[bi >> 6] = -INFINITY;  // remove selected
        }
        // softmax over the K selected scores (s_sk[0] is the max)
        const float m = s_sk[0];
        float e = (lane < KSEL) ? expf(s_sk[lane] - m) : 0.0f;
        float sum = e;
        #pragma unroll
        for (int o = 32; o > 0; o >>= 1) sum += __shfl_xor(sum, o, 64);
        if (lane < KSEL) s_w[lane] = e / sum;
    }
    __syncthreads();

    // ---- output: gather txt rows, scale by w, add segment embedding ----
    const float* txtb = ne + ((size_t)bh * SDIM + 1) * DDIM;
    float* outb = out_terms + (size_t)bh * KSEL * DDIM;
    const int d4 = tid & 63;
    #pragma unroll
    for (int p = 0; p < 8; ++p) {
        const int k    = p * 4 + (tid >> 6);
        const int kidx = s_kid[k];
        const float wk = s_w[k];
        float4 x  = reinterpret_cast<const float4*>(txtb + (size_t)kidx * DDIM)[d4];
        float4 sg = s_seg[d4];
        float4 r;
        r.x = x.x * wk + sg.x;
        r.y = x.y * wk + sg.y;
        r.z = x.z * wk + sg.z;
        r.w = x.w * wk + sg.w;
        reinterpret_cast<float4*>(outb + (size_t)k * DDIM)[d4] = r;
    }
    if (tid < KSEL) {
        const int kidx = s_kid[tid];
        out_mask[(size_t)bh * KSEL + tid] = am[(size_t)bh * SDIM + 1 + kidx];
        out_kid [(size_t)bh * KSEL + tid] = (float)kidx;
    }
}

extern "C" void kernel_launch(void* const* d_in, const int* in_sizes, int n_in,
                              void* d_out, int out_size, void* d_ws, size_t ws_size,
                              hipStream_t stream) {
    const float* nse = (const float*)d_in[0];  // news_selection_embedding
    const float* ne  = (const float*)d_in[1];  // news_embedding
    const float* ur  = (const float*)d_in[2];  // user_repr
    // d_in[3] = news_repr (unused by reference)
    const float* am  = (const float*)d_in[4];  // his_attn_mask
    const int*   rm  = (const int*)  d_in[5];  // his_refined_mask
    const float* seg = (const float*)d_in[6];  // segment_embedding

    const int B = in_sizes[2] / DDIM;          // user_repr: B*1*D
    const int H = in_sizes[6] / DDIM;          // segment_embedding: H*1*D

    float* out = (float*)d_out;
    const size_t n_terms = (size_t)B * H * KSEL * DDIM;
    const size_t n_mask  = (size_t)B * H * KSEL;

    matching_reducer_kernel<<<dim3(B * H), dim3(256), 0, stream>>>(
        nse, ne, ur, am, rm, seg,
        out, out + n_terms, out + n_terms + n_mask, H);
}

// Round 2
// 48.746 us; speedup vs baseline: 2.0164x; 2.0164x over previous
//
#include <hip/hip_runtime.h>
#include <math.h>

#define KSEL 32
#define DDIM 256
#define SDIM 256
#define SM1  255
#define EPSN 1e-12f

__global__ __launch_bounds__(256) void matching_reducer_kernel(
    const float* __restrict__ nse,   // (B,H,S,D) news_selection_embedding
    const float* __restrict__ ne,    // (B,H,S,D) news_embedding
    const float* __restrict__ ur,    // (B,1,D)   user_repr
    const float* __restrict__ am,    // (B,H,S)   his_attn_mask
    const int*   __restrict__ rm,    // (B,H,S)   his_refined_mask
    const float* __restrict__ seg,   // (H,1,D)   segment_embedding
    float* __restrict__ out_terms,   // (B,H*K,D)
    float* __restrict__ out_mask,    // (B,H*K)
    float* __restrict__ out_kid,     // (B,H*K)   indices as float
    int H)
{
    const int bh   = blockIdx.x;
    const int b    = bh / H;
    const int h    = bh % H;
    const int tid  = threadIdx.x;
    const int lane = tid & 63;
    const int wave = tid >> 6;
    const int g    = tid >> 4;   // 16 groups of 16 lanes
    const int t    = tid & 15;

    __shared__ float  s_scores[256];
    __shared__ int    s_rows[256];
    __shared__ int    s_wbase[4];
    __shared__ int    s_nv;
    __shared__ float  s_sk[KSEL];
    __shared__ int    s_kid[KSEL];
    __shared__ float  s_w[KSEL];
    __shared__ float4 s_seg[64];

    if (tid < 64) {
        s_seg[tid] = reinterpret_cast<const float4*>(seg + (size_t)h * DDIM)[tid];
    }
    s_scores[tid] = -INFINITY;

    // ---- validity + compaction: valid = refined_mask!=0 OR first-K slot ----
    const int* rmb = rm + (size_t)bh * SDIM + 1;
    const bool valid = (tid < SM1) && ((rmb[tid] != 0) || (tid < KSEL));
    const unsigned long long ball = __ballot(valid);
    if (lane == 0) s_wbase[wave] = __popcll(ball);

    // ---- q fragments: lane t holds q float4s {t, t+16, t+32, t+48} ----
    const float4* qv = reinterpret_cast<const float4*>(ur + (size_t)b * DDIM);
    float4 qf[4];
    #pragma unroll
    for (int j = 0; j < 4; ++j) qf[j] = qv[t + 16 * j];
    float qq = 0.f;
    #pragma unroll
    for (int j = 0; j < 4; ++j)
        qq += qf[j].x * qf[j].x + qf[j].y * qf[j].y + qf[j].z * qf[j].z + qf[j].w * qf[j].w;
    #pragma unroll
    for (int o = 8; o > 0; o >>= 1) qq += __shfl_xor(qq, o, 16);
    const float inv_q = 1.0f / fmaxf(sqrtf(qq), EPSN);

    __syncthreads();
    if (tid == 0) {
        int acc = 0;
        #pragma unroll
        for (int w2 = 0; w2 < 4; ++w2) { int c = s_wbase[w2]; s_wbase[w2] = acc; acc += c; }
        s_nv = acc;
    }
    __syncthreads();
    if (valid) {
        const int off = __popcll(ball & ((1ull << lane) - 1ull));
        s_rows[s_wbase[wave] + off] = tid;
    }
    __syncthreads();

    // ---- score pass over VALID rows only; group g owns rows i=g, g+16, ...
    //      2 rows in flight per group for latency hiding ----
    const int nv = s_nv;
    const float* selb = nse + ((size_t)bh * SDIM + 1) * DDIM;
    for (int i = g; i < nv; i += 32) {
        const int  rowA = s_rows[i];
        const bool hasB = (i + 16) < nv;
        const int  rowB = hasB ? s_rows[i + 16] : rowA;
        const float4* xa = reinterpret_cast<const float4*>(selb + (size_t)rowA * DDIM);
        const float4* xb = reinterpret_cast<const float4*>(selb + (size_t)rowB * DDIM);
        float4 va[4], vb[4];
        #pragma unroll
        for (int j = 0; j < 4; ++j) { va[j] = xa[t + 16 * j]; vb[j] = xb[t + 16 * j]; }
        float dotA = 0.f, ssA = 0.f, dotB = 0.f, ssB = 0.f;
        #pragma unroll
        for (int j = 0; j < 4; ++j) {
            dotA += va[j].x * qf[j].x + va[j].y * qf[j].y + va[j].z * qf[j].z + va[j].w * qf[j].w;
            ssA  += va[j].x * va[j].x + va[j].y * va[j].y + va[j].z * va[j].z + va[j].w * va[j].w;
            dotB += vb[j].x * qf[j].x + vb[j].y * qf[j].y + vb[j].z * qf[j].z + vb[j].w * qf[j].w;
            ssB  += vb[j].x * vb[j].x + vb[j].y * vb[j].y + vb[j].z * vb[j].z + vb[j].w * vb[j].w;
        }
        #pragma unroll
        for (int o = 8; o > 0; o >>= 1) {
            dotA += __shfl_xor(dotA, o, 16);
            ssA  += __shfl_xor(ssA,  o, 16);
            dotB += __shfl_xor(dotB, o, 16);
            ssB  += __shfl_xor(ssB,  o, 16);
        }
        if (t == 0) {
            s_scores[rowA] = dotA * inv_q / fmaxf(sqrtf(ssA), EPSN);
            if (hasB) s_scores[rowB] = dotB * inv_q / fmaxf(sqrtf(ssB), EPSN);
        }
    }
    __syncthreads();

    // ---- top-K (wave 0): iterative argmax, tie -> smallest index ----
    if (wave == 0) {
        float v[4];
        #pragma unroll
        for (int j = 0; j < 4; ++j) v[j] = s_scores[lane + 64 * j];
        for (int k = 0; k < KSEL; ++k) {
            float bv = v[0];
            int   bi = lane;
            #pragma unroll
            for (int j = 1; j < 4; ++j) {
                const int idx = lane + 64 * j;
                if (v[j] > bv || (v[j] == bv && idx < bi)) { bv = v[j]; bi = idx; }
            }
            #pragma unroll
            for (int o = 32; o > 0; o >>= 1) {
                float ov = __shfl_xor(bv, o, 64);
                int   oi = __shfl_xor(bi, o, 64);
                if (ov > bv || (ov == bv && oi < bi)) { bv = ov; bi = oi; }
            }
            if (lane == 0) { s_sk[k] = bv; s_kid[k] = bi; }
            if ((bi & 63) == lane) v[bi >> 6] = -INFINITY;
        }
        const float m = s_sk[0];
        float e = (lane < KSEL) ? expf(s_sk[lane] - m) : 0.0f;
        float sum = e;
        #pragma unroll
        for (int o = 32; o > 0; o >>= 1) sum += __shfl_xor(sum, o, 64);
        if (lane < KSEL) s_w[lane] = e / sum;
    }
    __syncthreads();

    // ---- output: gather txt rows, scale by w, add segment embedding ----
    const float* txtb = ne + ((size_t)bh * SDIM + 1) * DDIM;
    float* outb = out_terms + (size_t)bh * KSEL * DDIM;
    const int d4 = tid & 63;
    #pragma unroll
    for (int p = 0; p < 8; ++p) {
        const int k    = p * 4 + (tid >> 6);
        const int kidx = s_kid[k];
        const float wk = s_w[k];
        float4 x  = reinterpret_cast<const float4*>(txtb + (size_t)kidx * DDIM)[d4];
        float4 sg = s_seg[d4];
        float4 r;
        r.x = x.x * wk + sg.x;
        r.y = x.y * wk + sg.y;
        r.z = x.z * wk + sg.z;
        r.w = x.w * wk + sg.w;
        reinterpret_cast<float4*>(outb + (size_t)k * DDIM)[d4] = r;
    }
    if (tid < KSEL) {
        const int kidx = s_kid[tid];
        out_mask[(size_t)bh * KSEL + tid] = am[(size_t)bh * SDIM + 1 + kidx];
        out_kid [(size_t)bh * KSEL + tid] = (float)kidx;
    }
}

extern "C" void kernel_launch(void* const* d_in, const int* in_sizes, int n_in,
                              void* d_out, int out_size, void* d_ws, size_t ws_size,
                              hipStream_t stream) {
    const float* nse = (const float*)d_in[0];
    const float* ne  = (const float*)d_in[1];
    const float* ur  = (const float*)d_in[2];
    const float* am  = (const float*)d_in[4];
    const int*   rm  = (const int*)  d_in[5];
    const float* seg = (const float*)d_in[6];

    const int B = in_sizes[2] / DDIM;
    const int H = in_sizes[6] / DDIM;

    float* out = (float*)d_out;
    const size_t n_terms = (size_t)B * H * KSEL * DDIM;
    const size_t n_mask  = (size_t)B * H * KSEL;

    matching_reducer_kernel<<<dim3(B * H), dim3(256), 0, stream>>>(
        nse, ne, ur, am, rm, seg,
        out, out + n_terms, out + n_terms + n_mask, H);
}